// Round 2
// baseline (637.661 us; speedup 1.0000x reference)
//
#include <hip/hip_runtime.h>
#include <hip/hip_bf16.h>

typedef __hip_bfloat16 bf16;

constexpr int kB  = 2;
constexpr int kC  = 64;
constexpr int kCi = 16;
constexpr int kN  = 6400;   // 80*80
#define EPS_BN 1e-5f

__device__ __forceinline__ float b2f(bf16 v) { return __bfloat162float(v); }

// Dynamic-dtype input load / output store (flag: 1 = bf16, 0 = fp32)
__device__ __forceinline__ float ldin(const void* p, size_t i, int bf) {
    return bf ? __bfloat162float(((const bf16*)p)[i]) : ((const float*)p)[i];
}
__device__ __forceinline__ void stout(void* p, size_t i, float v, int bf) {
    if (bf) ((bf16*)p)[i] = __float2bfloat16(v);
    else    ((float*)p)[i] = v;
}

// ---------------------------------------------------------------------------
// Kernel 0: dtype detector. Reinterpret first 8192 halfwords of bfimg as
// bf16. True bf16 N(0,1) data: biased exp in ~[113,130] -> ~0% wild.
// fp32 data misread: low halves have uniform-random exponent -> ~50% wild.
// ---------------------------------------------------------------------------
__global__ __launch_bounds__(256)
void detect_kernel(const void* __restrict__ src, int* __restrict__ flag)
{
    __shared__ int cnt[256];
    const unsigned short* u = (const unsigned short*)src;
    int wild = 0;
    for (int i = threadIdx.x; i < 8192; i += 256) {
        int e = (u[i] >> 7) & 0xFF;
        if (e < 64 || e > 191) wild++;
    }
    cnt[threadIdx.x] = wild;
    __syncthreads();
    for (int s = 128; s > 0; s >>= 1) {
        if (threadIdx.x < s) cnt[threadIdx.x] += cnt[threadIdx.x + s];
        __syncthreads();
    }
    if (threadIdx.x == 0) *flag = (cnt[0] * 8 < 8192) ? 1 : 0; // <12.5% wild => bf16
}

// ---------------------------------------------------------------------------
// Kernel 1: four 1x1-conv projections -> fp32 proj[k][b][ci][n]
//   k=0: theta(bfimg), k=1: phi(bfimg), k=2: g(x), k=3: gbf(bfimg)
// ---------------------------------------------------------------------------
__global__ __launch_bounds__(256)
void proj_kernel(const void* __restrict__ bfimg, const void* __restrict__ x,
                 const void* __restrict__ w_theta, const void* __restrict__ b_theta,
                 const void* __restrict__ w_phi,   const void* __restrict__ b_phi,
                 const void* __restrict__ w_g,     const void* __restrict__ b_g,
                 const void* __restrict__ w_gbf,   const void* __restrict__ b_gbf,
                 const int* __restrict__ flagp, float* __restrict__ proj)
{
    const int bf = *flagp;
    int idx = blockIdx.x * 256 + threadIdx.x;        // over 4*kB*kCi*kN
    int n = idx % kN;
    int t = idx / kN;
    int c = t % kCi; t /= kCi;
    int b = t % kB;
    int k = t / kB;

    const void *src, *w, *bias;
    if (k == 0)      { src = bfimg; w = w_theta; bias = b_theta; }
    else if (k == 1) { src = bfimg; w = w_phi;   bias = b_phi;   }
    else if (k == 2) { src = x;     w = w_g;     bias = b_g;     }
    else             { src = bfimg; w = w_gbf;   bias = b_gbf;   }

    size_t sbase = (size_t)b * kC * kN + n;
    float acc;
    if (bf) {
        const bf16* sp = (const bf16*)src + sbase;
        const bf16* wp = (const bf16*)w + c * kC;
        acc = b2f(((const bf16*)bias)[c]);
#pragma unroll 8
        for (int ch = 0; ch < kC; ++ch)
            acc = fmaf(b2f(wp[ch]), b2f(sp[(size_t)ch * kN]), acc);
    } else {
        const float* sp = (const float*)src + sbase;
        const float* wp = (const float*)w + c * kC;
        acc = ((const float*)bias)[c];
#pragma unroll 8
        for (int ch = 0; ch < kC; ++ch)
            acc = fmaf(wp[ch], sp[(size_t)ch * kN], acc);
    }
    proj[idx] = acc;
}

// ---------------------------------------------------------------------------
// Kernel 2: one workgroup per (b, query). Full score row in LDS, exact
// softmax, dual-PV accumulate, fused w_W + BN + residual epilogue.
// Hot loops read only fp32 proj scratch -> dtype-independent.
// ---------------------------------------------------------------------------
__global__ __launch_bounds__(256)
void attn_kernel(const float* __restrict__ proj,
                 const void* __restrict__ bfimg, const void* __restrict__ x,
                 const void* __restrict__ w_W,  const void* __restrict__ b_W,
                 const void* __restrict__ gamma, const void* __restrict__ beta,
                 const void* __restrict__ mean,  const void* __restrict__ var,
                 const int* __restrict__ flagp, void* __restrict__ out)
{
    __shared__ float sc[kN];          // 25.6 KB score row
    __shared__ float thq[kCi];
    __shared__ float redw[4][32];     // per-wave partials
    __shared__ float yv[2 * kCi];
    __shared__ float sM, sL;

    const int bf   = *flagp;
    const int tid  = threadIdx.x;
    const int b    = blockIdx.x / kN;
    const int q    = blockIdx.x % kN;
    const int wave = tid >> 6;
    const int lane = tid & 63;

    const float* theta = proj + (size_t)(0 * kB + b) * kCi * kN;
    const float* phi   = proj + (size_t)(1 * kB + b) * kCi * kN;
    const float* gx    = proj + (size_t)(2 * kB + b) * kCi * kN;
    const float* gbf   = proj + (size_t)(3 * kB + b) * kCi * kN;

    if (tid < kCi) thq[tid] = theta[tid * kN + q];
    __syncthreads();
    float th[kCi];
#pragma unroll
    for (int c = 0; c < kCi; ++c) th[c] = thq[c];

    // ---- pass A: scores + local max ----
    float lmax = -1e30f;
    for (int m = tid; m < kN; m += 256) {
        float s = 0.f;
#pragma unroll
        for (int c = 0; c < kCi; ++c) s = fmaf(th[c], phi[c * kN + m], s);
        sc[m] = s;
        lmax = fmaxf(lmax, s);
    }
#pragma unroll
    for (int off = 32; off > 0; off >>= 1) lmax = fmaxf(lmax, __shfl_down(lmax, off));
    if (lane == 0) redw[wave][0] = lmax;
    __syncthreads();
    if (tid == 0) sM = fmaxf(fmaxf(redw[0][0], redw[1][0]),
                             fmaxf(redw[2][0], redw[3][0]));
    __syncthreads();
    const float M = sM;

    // ---- pass B: exp + local sum (each thread touches only the sc[m] it wrote)
    float lsum = 0.f;
    for (int m = tid; m < kN; m += 256) {
        float e = __expf(sc[m] - M);
        sc[m] = e;
        lsum += e;
    }
#pragma unroll
    for (int off = 32; off > 0; off >>= 1) lsum += __shfl_down(lsum, off);
    __syncthreads();                       // last read of redw (sM) is done
    if (lane == 0) redw[wave][0] = lsum;
    __syncthreads();
    if (tid == 0) sL = redw[0][0] + redw[1][0] + redw[2][0] + redw[3][0];
    __syncthreads();                       // sL visible; redw free again

    // ---- pass C: dual PV accumulate ----
    float acc[2 * kCi];
#pragma unroll
    for (int j = 0; j < 2 * kCi; ++j) acc[j] = 0.f;
    for (int m = tid; m < kN; m += 256) {
        float p = sc[m];
#pragma unroll
        for (int c = 0; c < kCi; ++c) acc[c]       = fmaf(p, gx[c * kN + m],  acc[c]);
#pragma unroll
        for (int c = 0; c < kCi; ++c) acc[kCi + c] = fmaf(p, gbf[c * kN + m], acc[kCi + c]);
    }
#pragma unroll
    for (int off = 32; off > 0; off >>= 1) {
#pragma unroll
        for (int j = 0; j < 2 * kCi; ++j) acc[j] += __shfl_down(acc[j], off);
    }
    if (lane == 0) {
#pragma unroll
        for (int j = 0; j < 2 * kCi; ++j) redw[wave][j] = acc[j];
    }
    __syncthreads();
    const float L = sL;
    if (tid < 2 * kCi)
        yv[tid] = (redw[0][tid] + redw[1][tid] + redw[2][tid] + redw[3][tid]) / L;
    __syncthreads();

    // ---- epilogue: z[co] = BN(w_W . y + b_W) + residual, both branches ----
    if (tid < 2 * kC) {
        int br = tid >> 6;          // 0: x-branch, 1: bfimg-branch
        int ch = tid & 63;
        const float* y = yv + br * kCi;
        float wy = ldin(b_W, ch, bf);
#pragma unroll
        for (int ci = 0; ci < kCi; ++ci)
            wy = fmaf(ldin(w_W, ch * kCi + ci, bf), y[ci], wy);
        float inv = rsqrtf(ldin(var, ch, bf) + EPS_BN);
        float z = (wy - ldin(mean, ch, bf)) * (ldin(gamma, ch, bf) * inv) + ldin(beta, ch, bf);
        const void* res = br ? bfimg : x;
        z += ldin(res, ((size_t)b * kC + ch) * kN + q, bf);
        stout(out, ((size_t)b * 2 * kC + tid) * kN + q, z, bf);
    }
}

// ---------------------------------------------------------------------------
extern "C" void kernel_launch(void* const* d_in, const int* in_sizes, int n_in,
                              void* d_out, int out_size, void* d_ws, size_t ws_size,
                              hipStream_t stream)
{
    const void* bfimg   = d_in[0];
    const void* x       = d_in[1];
    const void* w_theta = d_in[2];
    const void* b_theta = d_in[3];
    const void* w_phi   = d_in[4];
    const void* b_phi   = d_in[5];
    const void* w_g     = d_in[6];
    const void* b_g     = d_in[7];
    const void* w_gbf   = d_in[8];
    const void* b_gbf   = d_in[9];
    const void* w_W     = d_in[10];
    const void* b_W     = d_in[11];
    const void* gamma   = d_in[12];
    const void* beta    = d_in[13];
    const void* mean    = d_in[14];
    const void* var     = d_in[15];

    int*   flag = (int*)d_ws;                    // 4 B flag at offset 0
    float* proj = (float*)((char*)d_ws + 256);   // 4*kB*kCi*kN fp32 = 3.28 MB

    detect_kernel<<<1, 256, 0, stream>>>(bfimg, flag);

    proj_kernel<<<(4 * kB * kCi * kN) / 256, 256, 0, stream>>>(
        bfimg, x, w_theta, b_theta, w_phi, b_phi, w_g, b_g, w_gbf, b_gbf,
        flag, proj);

    attn_kernel<<<kB * kN, 256, 0, stream>>>(
        proj, bfimg, x, w_W, b_W, gamma, beta, mean, var, flag, d_out);
}